// Round 5
// baseline (2348.359 us; speedup 1.0000x reference)
//
#include <hip/hip_runtime.h>
#include <cstddef>

// Problem constants
#define B_  2
#define S_  2048
#define D_  1024
#define L_  4
#define H_  16
#define HD_ 64
#define MLP_ 4096
#define EPS_ 1e-5f

typedef __attribute__((ext_vector_type(8))) short  bf16x8;
typedef __attribute__((ext_vector_type(4))) float  f32x4;

// fp32 -> bf16 (RNE) and back, as bit patterns
__device__ __forceinline__ unsigned short f2bf(float x) {
    unsigned int u = __float_as_uint(x);
    u = (u + 0x7fffu + ((u >> 16) & 1u)) >> 16;
    return (unsigned short)u;
}
__device__ __forceinline__ float bf2f(unsigned short h) {
    return __uint_as_float(((unsigned int)h) << 16);
}

// ---------------------------------------------------------------------------
// Weight transpose+split pre-pass: W[K][N] fp32 -> Thi/Tlo[N][K] bf16 bits.
// 32x32 tiles via LDS. Runs every launch (graph-safe), ~15us total.
// ---------------------------------------------------------------------------
__global__ __launch_bounds__(256) void wconv_kernel(
    const float* __restrict__ W, unsigned short* __restrict__ Thi,
    unsigned short* __restrict__ Tlo, int K, int N)
{
    __shared__ float T[32][33];
    const int n0 = blockIdx.x * 32, k0 = blockIdx.y * 32;
    const int t = threadIdx.x;
    {
        const int r = t >> 3, c4 = (t & 7) * 4;
        const float4 w = *(const float4*)(W + (size_t)(k0 + r) * N + n0 + c4);
        T[r][c4 + 0] = w.x; T[r][c4 + 1] = w.y;
        T[r][c4 + 2] = w.z; T[r][c4 + 3] = w.w;
    }
    __syncthreads();
    {
        const int n = t >> 3, k4 = (t & 7) * 4;
        ushort4 h, l;
        float f;
        f = T[k4 + 0][n]; h.x = f2bf(f); l.x = f2bf(f - bf2f(h.x));
        f = T[k4 + 1][n]; h.y = f2bf(f); l.y = f2bf(f - bf2f(h.y));
        f = T[k4 + 2][n]; h.z = f2bf(f); l.z = f2bf(f - bf2f(h.z));
        f = T[k4 + 3][n]; h.w = f2bf(f); l.w = f2bf(f - bf2f(h.w));
        *(ushort4*)(Thi + (size_t)(n0 + n) * K + k0 + k4) = h;
        *(ushort4*)(Tlo + (size_t)(n0 + n) * K + k0 + k4) = l;
    }
}

// ---------------------------------------------------------------------------
// Split-bf16 MFMA GEMM: C[M,N] = act(A[M,K] @ W[K,N] + bias[N])
// A: fp32 (converted hi/lo in-loop). B: pre-split Bt_hi/Bt_lo [N][K] bf16.
// a*b ~= ah*bh + ah*bl + al*bh, all into one fp32 accumulator (err ~1.5e-5).
// 128x128 tile, BK=32, 256 thr = 4 waves (2x2), 64x64/wave = 4x4 frags of
// 16x16x32 MFMA. LDS rows padded to 40 bf16 (80B: 16B-aligned, bank
// stride 20 -> 2-way = free). EPI: 0 none, 1 relu, 2 gelu(erf).
// ---------------------------------------------------------------------------
template <int EPI>
__global__ __launch_bounds__(256) void gemm_bf16s_kernel(
    const float* __restrict__ A,
    const unsigned short* __restrict__ Bth, const unsigned short* __restrict__ Btl,
    const float* __restrict__ bias, float* __restrict__ C,
    int M, int N, int K)
{
    __shared__ unsigned short As_hi[128 * 40];
    __shared__ unsigned short As_lo[128 * 40];
    __shared__ unsigned short Bs_hi[128 * 40];
    __shared__ unsigned short Bs_lo[128 * 40];

    const int tid  = threadIdx.x;
    const int lane = tid & 63;
    const int wid  = tid >> 6;
    const int wr   = wid >> 1, wc = wid & 1;     // wave -> 64x64 quadrant
    const int l15  = lane & 15, chunk = lane >> 4;
    const int row0 = blockIdx.y * 128;
    const int col0 = blockIdx.x * 128;

    // fragment LDS base offsets (ushort units)
    const int a_off = (wr * 64 + l15) * 40 + chunk * 8;
    const int b_off = (wc * 64 + l15) * 40 + chunk * 8;

    f32x4 acc[4][4] = {};

    for (int k0 = 0; k0 < K; k0 += 32) {
        __syncthreads();
        // ---- stage A (fp32 -> hi/lo bf16), 128 rows x 32 k
        #pragma unroll
        for (int u = 0; u < 4; ++u) {
            const int idx = tid + u * 256;          // 0..1023
            const int r  = idx >> 3;
            const int kc = (idx & 7) * 4;
            const float4 a = *(const float4*)(A + (size_t)(row0 + r) * K + k0 + kc);
            ushort4 h, l;
            h.x = f2bf(a.x); l.x = f2bf(a.x - bf2f(h.x));
            h.y = f2bf(a.y); l.y = f2bf(a.y - bf2f(h.y));
            h.z = f2bf(a.z); l.z = f2bf(a.z - bf2f(h.z));
            h.w = f2bf(a.w); l.w = f2bf(a.w - bf2f(h.w));
            *(ushort4*)&As_hi[r * 40 + kc] = h;
            *(ushort4*)&As_lo[r * 40 + kc] = l;
        }
        // ---- stage B (pre-split bf16, k-contiguous), 128 cols x 32 k
        #pragma unroll
        for (int u = 0; u < 2; ++u) {
            const int idx = tid + u * 256;          // 0..511
            const int c  = idx >> 2;
            const int kc = (idx & 3) * 8;
            const size_t gb = (size_t)(col0 + c) * K + k0 + kc;
            *(uint4*)&Bs_hi[c * 40 + kc] = *(const uint4*)(Bth + gb);
            *(uint4*)&Bs_lo[c * 40 + kc] = *(const uint4*)(Btl + gb);
        }
        __syncthreads();

        // ---- fragments + 3-term MFMA
        bf16x8 ah[4], al[4], bh[4], bl[4];
        #pragma unroll
        for (int mi = 0; mi < 4; ++mi) {
            ah[mi] = *(const bf16x8*)&As_hi[a_off + mi * 640];
            al[mi] = *(const bf16x8*)&As_lo[a_off + mi * 640];
        }
        #pragma unroll
        for (int ni = 0; ni < 4; ++ni) {
            bh[ni] = *(const bf16x8*)&Bs_hi[b_off + ni * 640];
            bl[ni] = *(const bf16x8*)&Bs_lo[b_off + ni * 640];
        }
        #pragma unroll
        for (int mi = 0; mi < 4; ++mi)
            #pragma unroll
            for (int ni = 0; ni < 4; ++ni) {
                acc[mi][ni] = __builtin_amdgcn_mfma_f32_16x16x32_bf16(
                    ah[mi], bh[ni], acc[mi][ni], 0, 0, 0);
                acc[mi][ni] = __builtin_amdgcn_mfma_f32_16x16x32_bf16(
                    ah[mi], bl[ni], acc[mi][ni], 0, 0, 0);
                acc[mi][ni] = __builtin_amdgcn_mfma_f32_16x16x32_bf16(
                    al[mi], bh[ni], acc[mi][ni], 0, 0, 0);
            }
    }

    // ---- epilogue: bias + activation + store
    // D layout (m89): col = lane&15, row = (lane>>4)*4 + reg
    const int rbase = row0 + wr * 64 + (lane >> 4) * 4;
    const int cbase = col0 + wc * 64 + l15;
    #pragma unroll
    for (int mi = 0; mi < 4; ++mi) {
        #pragma unroll
        for (int reg = 0; reg < 4; ++reg) {
            const int gr = rbase + mi * 16 + reg;
            #pragma unroll
            for (int ni = 0; ni < 4; ++ni) {
                const int gc = cbase + ni * 16;
                float v = acc[mi][ni][reg] + bias[gc];
                if (EPI == 1) v = fmaxf(v, 0.f);
                else if (EPI == 2) v = 0.5f * v * (1.f + erff(v * 0.70710678118654752f));
                C[(size_t)gr * N + gc] = v;
            }
        }
    }
}

// ---------------------------------------------------------------------------
// NS[b,s,:] = sum_l normalize(layer_outputs[b,l,s,:])  (no gamma/beta)
// ---------------------------------------------------------------------------
__global__ __launch_bounds__(256) void grn_ns_kernel(
    const float* __restrict__ LO, float* __restrict__ NS)
{
    const int row = blockIdx.x;               // b*S + s
    const int b = row >> 11, s = row & (S_ - 1);
    const int tid = threadIdx.x;
    __shared__ float r1[4], r2[4];

    float acc[4] = {0.f, 0.f, 0.f, 0.f};
    #pragma unroll
    for (int l = 0; l < L_; ++l) {
        const float* xr = LO + ((size_t)((b * L_ + l) * S_ + s)) * D_;
        const float4 v = *(const float4*)(xr + tid * 4);
        float s1 = v.x + v.y + v.z + v.w;
        float s2 = v.x * v.x + v.y * v.y + v.z * v.z + v.w * v.w;
        #pragma unroll
        for (int off = 32; off >= 1; off >>= 1) {
            s1 += __shfl_xor(s1, off);
            s2 += __shfl_xor(s2, off);
        }
        if ((tid & 63) == 0) { r1[tid >> 6] = s1; r2[tid >> 6] = s2; }
        __syncthreads();
        s1 = r1[0] + r1[1] + r1[2] + r1[3];
        s2 = r2[0] + r2[1] + r2[2] + r2[3];
        __syncthreads();
        const float mu  = s1 * (1.f / D_);
        const float var = s2 * (1.f / D_) - mu * mu;
        const float rs  = rsqrtf(var + EPS_);
        acc[0] += (v.x - mu) * rs;
        acc[1] += (v.y - mu) * rs;
        acc[2] += (v.z - mu) * rs;
        acc[3] += (v.w - mu) * rs;
    }
    float4 o = {acc[0], acc[1], acc[2], acc[3]};
    *(float4*)(NS + (size_t)row * D_ + tid * 4) = o;
}

// ---------------------------------------------------------------------------
// out[b,s,d] = sum_l P[(b,l,s),d] + NS[b,s,d]*g[d] + 4*be[d]
// ---------------------------------------------------------------------------
__global__ __launch_bounds__(256) void grn_reduce_kernel(
    const float* __restrict__ P, const float* __restrict__ NS,
    const float* __restrict__ g, const float* __restrict__ be,
    float* __restrict__ out)
{
    const size_t i4 = (size_t)blockIdx.x * 256 + threadIdx.x;  // float4 index
    const int d4 = (int)(i4 & (D_ / 4 - 1));
    const size_t row = i4 >> 8;                                // b*S + s
    const int b = (int)(row >> 11), s = (int)(row & (S_ - 1));

    float4 a = {0.f, 0.f, 0.f, 0.f};
    #pragma unroll
    for (int l = 0; l < L_; ++l) {
        const float4 w = *(const float4*)(P + ((size_t)((b * L_ + l) * S_ + s)) * D_ + d4 * 4);
        a.x += w.x; a.y += w.y; a.z += w.z; a.w += w.w;
    }
    const float4 n  = *(const float4*)(NS + row * D_ + d4 * 4);
    const float4 gg = *(const float4*)(g + d4 * 4);
    const float4 bb = *(const float4*)(be + d4 * 4);
    float4 o;
    o.x = a.x + n.x * gg.x + 4.f * bb.x;
    o.y = a.y + n.y * gg.y + 4.f * bb.y;
    o.z = a.z + n.z * gg.z + 4.f * bb.z;
    o.w = a.w + n.w * gg.w + 4.f * bb.w;
    *(float4*)(out + row * D_ + d4 * 4) = o;
}

// ---------------------------------------------------------------------------
// Flash attention, fp32 (unchanged from audited baseline).
// ---------------------------------------------------------------------------
#define TQ_ 32
#define KT_ 64

__global__ __launch_bounds__(256) void attn_kernel(
    const float* __restrict__ Q, const float* __restrict__ K,
    const float* __restrict__ V, float* __restrict__ O)
{
    __shared__ float Qs[TQ_ * 64];        // swizzled
    __shared__ float Ks[KT_ * 64];        // swizzled
    __shared__ float Vs[KT_ * 68];        // padded
    __shared__ float Ps[TQ_ * 68];        // padded
    __shared__ float mS[TQ_], lS[TQ_], cS[TQ_];

    const int tid = threadIdx.x;
    const int bh = blockIdx.y;
    const int b = bh >> 4, h = bh & 15;
    const int q0 = blockIdx.x * TQ_;
    const float scale = 0.125f;           // HD^-0.5

    const float* Qg = Q + ((size_t)b * S_ + q0) * D_ + h * HD_;
    const float* Kg = K + (size_t)b * S_ * D_ + h * HD_;
    const float* Vg = V + (size_t)b * S_ * D_ + h * HD_;

    for (int i = tid; i < TQ_ * 16; i += 256) {
        const int r = i >> 4, dv = i & 15;
        float4 v = *(const float4*)(Qg + (size_t)r * D_ + dv * 4);
        v.x *= scale; v.y *= scale; v.z *= scale; v.w *= scale;
        *(float4*)&Qs[r * 64 + ((dv ^ ((r >> 1) & 15)) << 2)] = v;
    }
    if (tid < TQ_) { mS[tid] = -1e30f; lS[tid] = 0.f; }

    const int qo = tid >> 3, pp = tid & 7;     // PV ownership
    const int tq2 = tid >> 4, tk4 = tid & 15;  // score ownership
    float4 o0 = {0, 0, 0, 0}, o1 = {0, 0, 0, 0};

    for (int kt = 0; kt < S_; kt += KT_) {
        __syncthreads();
        for (int i = tid; i < KT_ * 16; i += 256) {
            const int r = i >> 4, dv = i & 15;
            const float4 kv = *(const float4*)(Kg + (size_t)(kt + r) * D_ + dv * 4);
            *(float4*)&Ks[r * 64 + ((dv ^ ((r >> 2) & 15)) << 2)] = kv;
            const float4 vv = *(const float4*)(Vg + (size_t)(kt + r) * D_ + dv * 4);
            *(float4*)&Vs[r * 68 + dv * 4] = vv;
        }
        __syncthreads();

        float sc[2][4] = {};
        #pragma unroll
        for (int dv = 0; dv < 16; ++dv) {
            const int dq = (dv ^ tq2) << 2;
            const int dk = (dv ^ tk4) << 2;
            const float4 q0v = *(const float4*)&Qs[(2 * tq2 + 0) * 64 + dq];
            const float4 q1v = *(const float4*)&Qs[(2 * tq2 + 1) * 64 + dq];
            const float4 k0v = *(const float4*)&Ks[(4 * tk4 + 0) * 64 + dk];
            const float4 k1v = *(const float4*)&Ks[(4 * tk4 + 1) * 64 + dk];
            const float4 k2v = *(const float4*)&Ks[(4 * tk4 + 2) * 64 + dk];
            const float4 k3v = *(const float4*)&Ks[(4 * tk4 + 3) * 64 + dk];
            sc[0][0] += q0v.x*k0v.x + q0v.y*k0v.y + q0v.z*k0v.z + q0v.w*k0v.w;
            sc[0][1] += q0v.x*k1v.x + q0v.y*k1v.y + q0v.z*k1v.z + q0v.w*k1v.w;
            sc[0][2] += q0v.x*k2v.x + q0v.y*k2v.y + q0v.z*k2v.z + q0v.w*k2v.w;
            sc[0][3] += q0v.x*k3v.x + q0v.y*k3v.y + q0v.z*k3v.z + q0v.w*k3v.w;
            sc[1][0] += q1v.x*k0v.x + q1v.y*k0v.y + q1v.z*k0v.z + q1v.w*k0v.w;
            sc[1][1] += q1v.x*k1v.x + q1v.y*k1v.y + q1v.z*k1v.z + q1v.w*k1v.w;
            sc[1][2] += q1v.x*k2v.x + q1v.y*k2v.y + q1v.z*k2v.z + q1v.w*k2v.w;
            sc[1][3] += q1v.x*k3v.x + q1v.y*k3v.y + q1v.z*k3v.z + q1v.w*k3v.w;
        }
        #pragma unroll
        for (int qq = 0; qq < 2; ++qq)
            #pragma unroll
            for (int j = 0; j < 4; ++j)
                Ps[(2 * tq2 + qq) * 68 + 4 * tk4 + j] = sc[qq][j];
        __syncthreads();

        {
            const int r = tid >> 3, p8 = tid & 7;
            float4 e0 = *(const float4*)&Ps[r * 68 + p8 * 8];
            float4 e1 = *(const float4*)&Ps[r * 68 + p8 * 8 + 4];
            float tm = fmaxf(fmaxf(fmaxf(e0.x, e0.y), fmaxf(e0.z, e0.w)),
                             fmaxf(fmaxf(e1.x, e1.y), fmaxf(e1.z, e1.w)));
            tm = fmaxf(tm, __shfl_xor(tm, 1));
            tm = fmaxf(tm, __shfl_xor(tm, 2));
            tm = fmaxf(tm, __shfl_xor(tm, 4));
            const float mold = mS[r];
            const float mnew = fmaxf(mold, tm);
            e0.x = __expf(e0.x - mnew); e0.y = __expf(e0.y - mnew);
            e0.z = __expf(e0.z - mnew); e0.w = __expf(e0.w - mnew);
            e1.x = __expf(e1.x - mnew); e1.y = __expf(e1.y - mnew);
            e1.z = __expf(e1.z - mnew); e1.w = __expf(e1.w - mnew);
            float ts = e0.x + e0.y + e0.z + e0.w + e1.x + e1.y + e1.z + e1.w;
            ts += __shfl_xor(ts, 1);
            ts += __shfl_xor(ts, 2);
            ts += __shfl_xor(ts, 4);
            *(float4*)&Ps[r * 68 + p8 * 8]     = e0;
            *(float4*)&Ps[r * 68 + p8 * 8 + 4] = e1;
            if (p8 == 0) {
                const float c = __expf(mold - mnew);
                cS[r] = c;
                lS[r] = lS[r] * c + ts;
                mS[r] = mnew;
            }
        }
        __syncthreads();

        {
            const float cc = cS[qo];
            o0.x *= cc; o0.y *= cc; o0.z *= cc; o0.w *= cc;
            o1.x *= cc; o1.y *= cc; o1.z *= cc; o1.w *= cc;
            #pragma unroll 4
            for (int j = 0; j < KT_; ++j) {
                const float p = Ps[qo * 68 + j];
                const float4 v0 = *(const float4*)&Vs[j * 68 + pp * 8];
                const float4 v1 = *(const float4*)&Vs[j * 68 + pp * 8 + 4];
                o0.x = fmaf(p, v0.x, o0.x); o0.y = fmaf(p, v0.y, o0.y);
                o0.z = fmaf(p, v0.z, o0.z); o0.w = fmaf(p, v0.w, o0.w);
                o1.x = fmaf(p, v1.x, o1.x); o1.y = fmaf(p, v1.y, o1.y);
                o1.z = fmaf(p, v1.z, o1.z); o1.w = fmaf(p, v1.w, o1.w);
            }
        }
    }

    const float inv = 1.f / lS[qo];
    o0.x *= inv; o0.y *= inv; o0.z *= inv; o0.w *= inv;
    o1.x *= inv; o1.y *= inv; o1.z *= inv; o1.w *= inv;
    float* Og = O + ((size_t)b * S_ + q0 + qo) * D_ + h * HD_ + pp * 8;
    *(float4*)Og       = o0;
    *(float4*)(Og + 4) = o1;
}

// ---------------------------------------------------------------------------
// out[row,:] = R[row,:] + LN(Y[row,:]) * g + beta   (one block per row)
// ---------------------------------------------------------------------------
__global__ __launch_bounds__(256) void add_ln_kernel(
    const float* __restrict__ Y, const float* __restrict__ R,
    const float* __restrict__ g, const float* __restrict__ beta,
    float* __restrict__ out)
{
    const int row = blockIdx.x;
    const int tid = threadIdx.x;
    __shared__ float r1[4], r2[4];

    const float4 v = *(const float4*)(Y + (size_t)row * D_ + tid * 4);
    float s1 = v.x + v.y + v.z + v.w;
    float s2 = v.x * v.x + v.y * v.y + v.z * v.z + v.w * v.w;
    #pragma unroll
    for (int off = 32; off >= 1; off >>= 1) {
        s1 += __shfl_xor(s1, off);
        s2 += __shfl_xor(s2, off);
    }
    if ((tid & 63) == 0) { r1[tid >> 6] = s1; r2[tid >> 6] = s2; }
    __syncthreads();
    s1 = r1[0] + r1[1] + r1[2] + r1[3];
    s2 = r2[0] + r2[1] + r2[2] + r2[3];
    const float mu  = s1 * (1.f / D_);
    const float var = s2 * (1.f / D_) - mu * mu;
    const float rs  = rsqrtf(var + EPS_);

    const float4 rr = *(const float4*)(R + (size_t)row * D_ + tid * 4);
    const float4 gg = *(const float4*)(g + tid * 4);
    const float4 bb = *(const float4*)(beta + tid * 4);
    float4 o;
    o.x = rr.x + (v.x - mu) * rs * gg.x + bb.x;
    o.y = rr.y + (v.y - mu) * rs * gg.y + bb.y;
    o.z = rr.z + (v.z - mu) * rs * gg.z + bb.z;
    o.w = rr.w + (v.w - mu) * rs * gg.w + bb.w;
    *(float4*)(out + (size_t)row * D_ + tid * 4) = o;
}

// ---------------------------------------------------------------------------
extern "C" void kernel_launch(void* const* d_in, const int* in_sizes, int n_in,
                              void* d_out, int out_size, void* d_ws, size_t ws_size,
                              hipStream_t stream)
{
    const float* x  = (const float*)d_in[0];
    const float* LO = (const float*)d_in[1];
    const float* Wq  = (const float*)d_in[2];
    const float* bq_ = (const float*)d_in[3];
    const float* gq  = (const float*)d_in[4];
    const float* beq = (const float*)d_in[5];
    const float* Wk  = (const float*)d_in[6];
    const float* bk_ = (const float*)d_in[7];
    const float* gk  = (const float*)d_in[8];
    const float* bek = (const float*)d_in[9];
    const float* Wv  = (const float*)d_in[10];
    const float* bv_ = (const float*)d_in[11];
    const float* gv  = (const float*)d_in[12];
    const float* bev = (const float*)d_in[13];
    const float* Wo  = (const float*)d_in[14];
    const float* bo  = (const float*)d_in[15];
    const float* ang = (const float*)d_in[16];
    const float* anb = (const float*)d_in[17];
    const float* W1  = (const float*)d_in[18];
    const float* b1  = (const float*)d_in[19];
    const float* W2  = (const float*)d_in[20];
    const float* b2  = (const float*)d_in[21];
    const float* fng = (const float*)d_in[22];
    const float* fnb = (const float*)d_in[23];

    const size_t BS  = (size_t)B_ * S_;          // 4096 rows
    const size_t SEG = BS * D_;                  // 4M floats
    float* ws  = (float*)d_ws;
    float* ns   = ws;                            // 4M  (later: attn out)
    float* bufq = ws + SEG;                      // 4M  (later: attn proj out)
    float* bufk = ws + 2 * SEG;                  // 4M  (later: resid1)
    float* bufv = ws + 3 * SEG;                  // 4M  (later: ffn2 out)
    float* big  = ws + 4 * SEG;                  // 16M (GRN staging / FFN hidden)

    // Pre-split transposed weights (bf16 bits), after the fp32 region (128MB)
    unsigned short* wt = (unsigned short*)(ws + 8 * SEG);   // 8*SEG = 32M floats
    const size_t MM = 1048576;                               // 1M elements
    unsigned short* wtq_h = wt;            unsigned short* wtq_l = wt + MM;
    unsigned short* wtk_h = wt + 2 * MM;   unsigned short* wtk_l = wt + 3 * MM;
    unsigned short* wtv_h = wt + 4 * MM;   unsigned short* wtv_l = wt + 5 * MM;
    unsigned short* wto_h = wt + 6 * MM;   unsigned short* wto_l = wt + 7 * MM;
    unsigned short* w1_h  = wt + 8 * MM;   unsigned short* w1_l  = wt + 12 * MM;
    unsigned short* w2_h  = wt + 16 * MM;  unsigned short* w2_l  = wt + 20 * MM;

    const dim3 blk(256);

    // 0. weight transpose + hi/lo split (cheap, every launch; graph-safe)
    wconv_kernel<<<dim3(32, 32),  blk, 0, stream>>>(Wq, wtq_h, wtq_l, D_, D_);
    wconv_kernel<<<dim3(32, 32),  blk, 0, stream>>>(Wk, wtk_h, wtk_l, D_, D_);
    wconv_kernel<<<dim3(32, 32),  blk, 0, stream>>>(Wv, wtv_h, wtv_l, D_, D_);
    wconv_kernel<<<dim3(32, 32),  blk, 0, stream>>>(Wo, wto_h, wto_l, D_, D_);
    wconv_kernel<<<dim3(128, 32), blk, 0, stream>>>(W1, w1_h,  w1_l,  D_, MLP_);
    wconv_kernel<<<dim3(32, 128), blk, 0, stream>>>(W2, w2_h,  w2_l,  MLP_, D_);

    // 1. shared normalized sum
    grn_ns_kernel<<<dim3(BS), blk, 0, stream>>>(LO, ns);

    // 2. GRN q/k/v: relu MFMA-GEMM (M=16384) then reduce over L + norm branch
    const unsigned short* Wh[3] = {wtq_h, wtk_h, wtv_h};
    const unsigned short* Wl[3] = {wtq_l, wtk_l, wtv_l};
    const float* bp[3]  = {bq_, bk_, bv_};
    const float* gp[3]  = {gq, gk, gv};
    const float* bep[3] = {beq, bek, bev};
    float* outp[3] = {bufq, bufk, bufv};
    for (int p = 0; p < 3; ++p) {
        gemm_bf16s_kernel<1><<<dim3(D_ / 128, (B_ * L_ * S_) / 128), blk, 0, stream>>>(
            LO, Wh[p], Wl[p], bp[p], big, B_ * L_ * S_, D_, D_);
        grn_reduce_kernel<<<dim3(BS), blk, 0, stream>>>(big, ns, gp[p], bep[p], outp[p]);
    }

    // 3. attention -> ns (reused)
    attn_kernel<<<dim3(S_ / TQ_, B_ * H_), blk, 0, stream>>>(bufq, bufk, bufv, ns);

    // 4. attn out projection -> bufq (reused)
    gemm_bf16s_kernel<0><<<dim3(D_ / 128, BS / 128), blk, 0, stream>>>(
        ns, wto_h, wto_l, bo, bufq, (int)BS, D_, D_);

    // 5. resid1 = x + LN(attn_proj) -> bufk (reused)
    add_ln_kernel<<<dim3(BS), blk, 0, stream>>>(bufq, x, ang, anb, bufk);

    // 6. FFN1: gelu(resid1 @ W1 + b1) -> big [4096, 4096]
    gemm_bf16s_kernel<2><<<dim3(MLP_ / 128, BS / 128), blk, 0, stream>>>(
        bufk, w1_h, w1_l, b1, big, (int)BS, MLP_, D_);

    // 7. FFN2: big @ W2 + b2 -> bufv (reused)
    gemm_bf16s_kernel<0><<<dim3(D_ / 128, BS / 128), blk, 0, stream>>>(
        big, w2_h, w2_l, b2, bufv, (int)BS, D_, MLP_);

    // 8. out = resid1 + LN(ffn2)
    add_ln_kernel<<<dim3(BS), blk, 0, stream>>>(bufv, bufk, fng, fnb, (float*)d_out);
}

// Round 6
// 1222.669 us; speedup vs baseline: 1.9207x; 1.9207x over previous
//
#include <hip/hip_runtime.h>
#include <cstddef>

// Problem constants
#define B_  2
#define S_  2048
#define D_  1024
#define L_  4
#define H_  16
#define HD_ 64
#define MLP_ 4096
#define EPS_ 1e-5f

typedef __attribute__((ext_vector_type(8))) short  bf16x8;
typedef __attribute__((ext_vector_type(4))) float  f32x4;

// fp32 -> bf16 (RNE) and back, as bit patterns
__device__ __forceinline__ unsigned short f2bf(float x) {
    unsigned int u = __float_as_uint(x);
    u = (u + 0x7fffu + ((u >> 16) & 1u)) >> 16;
    return (unsigned short)u;
}
__device__ __forceinline__ float bf2f(unsigned short h) {
    return __uint_as_float(((unsigned int)h) << 16);
}

// ---------------------------------------------------------------------------
// Weight transpose+split pre-pass: W[K][N] fp32 -> Thi/Tlo[N][K] bf16 bits.
// ---------------------------------------------------------------------------
__global__ __launch_bounds__(256) void wconv_kernel(
    const float* __restrict__ W, unsigned short* __restrict__ Thi,
    unsigned short* __restrict__ Tlo, int K, int N)
{
    __shared__ float T[32][33];
    const int n0 = blockIdx.x * 32, k0 = blockIdx.y * 32;
    const int t = threadIdx.x;
    {
        const int r = t >> 3, c4 = (t & 7) * 4;
        const float4 w = *(const float4*)(W + (size_t)(k0 + r) * N + n0 + c4);
        T[r][c4 + 0] = w.x; T[r][c4 + 1] = w.y;
        T[r][c4 + 2] = w.z; T[r][c4 + 3] = w.w;
    }
    __syncthreads();
    {
        const int n = t >> 3, k4 = (t & 7) * 4;
        ushort4 h, l;
        float f;
        f = T[k4 + 0][n]; h.x = f2bf(f); l.x = f2bf(f - bf2f(h.x));
        f = T[k4 + 1][n]; h.y = f2bf(f); l.y = f2bf(f - bf2f(h.y));
        f = T[k4 + 2][n]; h.z = f2bf(f); l.z = f2bf(f - bf2f(h.z));
        f = T[k4 + 3][n]; h.w = f2bf(f); l.w = f2bf(f - bf2f(h.w));
        *(ushort4*)(Thi + (size_t)(n0 + n) * K + k0 + k4) = h;
        *(ushort4*)(Tlo + (size_t)(n0 + n) * K + k0 + k4) = l;
    }
}

// ---------------------------------------------------------------------------
// Split-bf16 MFMA GEMM (validated round 5). EPI: 0 none, 1 relu, 2 gelu.
// ---------------------------------------------------------------------------
template <int EPI>
__global__ __launch_bounds__(256) void gemm_bf16s_kernel(
    const float* __restrict__ A,
    const unsigned short* __restrict__ Bth, const unsigned short* __restrict__ Btl,
    const float* __restrict__ bias, float* __restrict__ C,
    int M, int N, int K)
{
    __shared__ unsigned short As_hi[128 * 40];
    __shared__ unsigned short As_lo[128 * 40];
    __shared__ unsigned short Bs_hi[128 * 40];
    __shared__ unsigned short Bs_lo[128 * 40];

    const int tid  = threadIdx.x;
    const int lane = tid & 63;
    const int wid  = tid >> 6;
    const int wr   = wid >> 1, wc = wid & 1;
    const int l15  = lane & 15, chunk = lane >> 4;
    const int row0 = blockIdx.y * 128;
    const int col0 = blockIdx.x * 128;

    const int a_off = (wr * 64 + l15) * 40 + chunk * 8;
    const int b_off = (wc * 64 + l15) * 40 + chunk * 8;

    f32x4 acc[4][4] = {};

    for (int k0 = 0; k0 < K; k0 += 32) {
        __syncthreads();
        #pragma unroll
        for (int u = 0; u < 4; ++u) {
            const int idx = tid + u * 256;
            const int r  = idx >> 3;
            const int kc = (idx & 7) * 4;
            const float4 a = *(const float4*)(A + (size_t)(row0 + r) * K + k0 + kc);
            ushort4 h, l;
            h.x = f2bf(a.x); l.x = f2bf(a.x - bf2f(h.x));
            h.y = f2bf(a.y); l.y = f2bf(a.y - bf2f(h.y));
            h.z = f2bf(a.z); l.z = f2bf(a.z - bf2f(h.z));
            h.w = f2bf(a.w); l.w = f2bf(a.w - bf2f(h.w));
            *(ushort4*)&As_hi[r * 40 + kc] = h;
            *(ushort4*)&As_lo[r * 40 + kc] = l;
        }
        #pragma unroll
        for (int u = 0; u < 2; ++u) {
            const int idx = tid + u * 256;
            const int c  = idx >> 2;
            const int kc = (idx & 3) * 8;
            const size_t gb = (size_t)(col0 + c) * K + k0 + kc;
            *(uint4*)&Bs_hi[c * 40 + kc] = *(const uint4*)(Bth + gb);
            *(uint4*)&Bs_lo[c * 40 + kc] = *(const uint4*)(Btl + gb);
        }
        __syncthreads();

        bf16x8 ah[4], al[4], bh[4], bl[4];
        #pragma unroll
        for (int mi = 0; mi < 4; ++mi) {
            ah[mi] = *(const bf16x8*)&As_hi[a_off + mi * 640];
            al[mi] = *(const bf16x8*)&As_lo[a_off + mi * 640];
        }
        #pragma unroll
        for (int ni = 0; ni < 4; ++ni) {
            bh[ni] = *(const bf16x8*)&Bs_hi[b_off + ni * 640];
            bl[ni] = *(const bf16x8*)&Bs_lo[b_off + ni * 640];
        }
        #pragma unroll
        for (int mi = 0; mi < 4; ++mi)
            #pragma unroll
            for (int ni = 0; ni < 4; ++ni) {
                acc[mi][ni] = __builtin_amdgcn_mfma_f32_16x16x32_bf16(
                    ah[mi], bh[ni], acc[mi][ni], 0, 0, 0);
                acc[mi][ni] = __builtin_amdgcn_mfma_f32_16x16x32_bf16(
                    ah[mi], bl[ni], acc[mi][ni], 0, 0, 0);
                acc[mi][ni] = __builtin_amdgcn_mfma_f32_16x16x32_bf16(
                    al[mi], bh[ni], acc[mi][ni], 0, 0, 0);
            }
    }

    const int rbase = row0 + wr * 64 + (lane >> 4) * 4;
    const int cbase = col0 + wc * 64 + l15;
    #pragma unroll
    for (int mi = 0; mi < 4; ++mi) {
        #pragma unroll
        for (int reg = 0; reg < 4; ++reg) {
            const int gr = rbase + mi * 16 + reg;
            #pragma unroll
            for (int ni = 0; ni < 4; ++ni) {
                const int gc = cbase + ni * 16;
                float v = acc[mi][ni][reg] + bias[gc];
                if (EPI == 1) v = fmaxf(v, 0.f);
                else if (EPI == 2) v = 0.5f * v * (1.f + erff(v * 0.70710678118654752f));
                C[(size_t)gr * N + gc] = v;
            }
        }
    }
}

// ---------------------------------------------------------------------------
// NS[b,s,:] = sum_l normalize(layer_outputs[b,l,s,:])
// ---------------------------------------------------------------------------
__global__ __launch_bounds__(256) void grn_ns_kernel(
    const float* __restrict__ LO, float* __restrict__ NS)
{
    const int row = blockIdx.x;
    const int b = row >> 11, s = row & (S_ - 1);
    const int tid = threadIdx.x;
    __shared__ float r1[4], r2[4];

    float acc[4] = {0.f, 0.f, 0.f, 0.f};
    #pragma unroll
    for (int l = 0; l < L_; ++l) {
        const float* xr = LO + ((size_t)((b * L_ + l) * S_ + s)) * D_;
        const float4 v = *(const float4*)(xr + tid * 4);
        float s1 = v.x + v.y + v.z + v.w;
        float s2 = v.x * v.x + v.y * v.y + v.z * v.z + v.w * v.w;
        #pragma unroll
        for (int off = 32; off >= 1; off >>= 1) {
            s1 += __shfl_xor(s1, off);
            s2 += __shfl_xor(s2, off);
        }
        if ((tid & 63) == 0) { r1[tid >> 6] = s1; r2[tid >> 6] = s2; }
        __syncthreads();
        s1 = r1[0] + r1[1] + r1[2] + r1[3];
        s2 = r2[0] + r2[1] + r2[2] + r2[3];
        __syncthreads();
        const float mu  = s1 * (1.f / D_);
        const float var = s2 * (1.f / D_) - mu * mu;
        const float rs  = rsqrtf(var + EPS_);
        acc[0] += (v.x - mu) * rs;
        acc[1] += (v.y - mu) * rs;
        acc[2] += (v.z - mu) * rs;
        acc[3] += (v.w - mu) * rs;
    }
    float4 o = {acc[0], acc[1], acc[2], acc[3]};
    *(float4*)(NS + (size_t)row * D_ + tid * 4) = o;
}

// ---------------------------------------------------------------------------
// out[b,s,d] = sum_l P[(b,l,s),d] + NS[b,s,d]*g[d] + 4*be[d]
// ---------------------------------------------------------------------------
__global__ __launch_bounds__(256) void grn_reduce_kernel(
    const float* __restrict__ P, const float* __restrict__ NS,
    const float* __restrict__ g, const float* __restrict__ be,
    float* __restrict__ out)
{
    const size_t i4 = (size_t)blockIdx.x * 256 + threadIdx.x;
    const int d4 = (int)(i4 & (D_ / 4 - 1));
    const size_t row = i4 >> 8;
    const int b = (int)(row >> 11), s = (int)(row & (S_ - 1));

    float4 a = {0.f, 0.f, 0.f, 0.f};
    #pragma unroll
    for (int l = 0; l < L_; ++l) {
        const float4 w = *(const float4*)(P + ((size_t)((b * L_ + l) * S_ + s)) * D_ + d4 * 4);
        a.x += w.x; a.y += w.y; a.z += w.z; a.w += w.w;
    }
    const float4 n  = *(const float4*)(NS + row * D_ + d4 * 4);
    const float4 gg = *(const float4*)(g + d4 * 4);
    const float4 bb = *(const float4*)(be + d4 * 4);
    float4 o;
    o.x = a.x + n.x * gg.x + 4.f * bb.x;
    o.y = a.y + n.y * gg.y + 4.f * bb.y;
    o.z = a.z + n.z * gg.z + 4.f * bb.z;
    o.w = a.w + n.w * gg.w + 4.f * bb.w;
    *(float4*)(out + row * D_ + d4 * 4) = o;
}

// ---------------------------------------------------------------------------
// K/V split pre-pass: K[b,s,h*64+d] fp32 -> Kh/Kl[bh][s][d] bf16;
//                     V -> Vth/Vtl[bh][d][s] (transposed) bf16.
// ---------------------------------------------------------------------------
__global__ __launch_bounds__(256) void kvconv_kernel(
    const float* __restrict__ Kin, const float* __restrict__ Vin,
    unsigned short* __restrict__ Kh, unsigned short* __restrict__ Kl,
    unsigned short* __restrict__ Vth, unsigned short* __restrict__ Vtl)
{
    __shared__ float T[64][68];
    const int t = threadIdx.x;
    const int st = blockIdx.x;            // s-tile (64 rows)
    const int bh = blockIdx.y;
    const int b = bh >> 4, h = bh & 15;
    const int s0 = st * 64;

    #pragma unroll
    for (int u = 0; u < 4; ++u) {
        const int idx = t + u * 256;      // 0..1023
        const int r  = idx >> 4;          // s row 0..63
        const int c4 = (idx & 15) * 4;    // d 0..60
        const size_t src = ((size_t)(b * S_ + s0 + r)) * D_ + h * 64 + c4;
        const float4 kf = *(const float4*)(Kin + src);
        ushort4 hh, ll;
        hh.x = f2bf(kf.x); ll.x = f2bf(kf.x - bf2f(hh.x));
        hh.y = f2bf(kf.y); ll.y = f2bf(kf.y - bf2f(hh.y));
        hh.z = f2bf(kf.z); ll.z = f2bf(kf.z - bf2f(hh.z));
        hh.w = f2bf(kf.w); ll.w = f2bf(kf.w - bf2f(hh.w));
        const size_t kd = ((size_t)bh * S_ + s0 + r) * 64 + c4;
        *(ushort4*)(Kh + kd) = hh;
        *(ushort4*)(Kl + kd) = ll;
        const float4 vf = *(const float4*)(Vin + src);
        T[r][c4 + 0] = vf.x; T[r][c4 + 1] = vf.y;
        T[r][c4 + 2] = vf.z; T[r][c4 + 3] = vf.w;
    }
    __syncthreads();
    #pragma unroll
    for (int u = 0; u < 4; ++u) {
        const int idx = t + u * 256;
        const int d  = idx >> 4;          // 0..63
        const int s4 = (idx & 15) * 4;    // 0..60
        ushort4 hh, ll;
        float f;
        f = T[s4 + 0][d]; hh.x = f2bf(f); ll.x = f2bf(f - bf2f(hh.x));
        f = T[s4 + 1][d]; hh.y = f2bf(f); ll.y = f2bf(f - bf2f(hh.y));
        f = T[s4 + 2][d]; hh.z = f2bf(f); ll.z = f2bf(f - bf2f(hh.z));
        f = T[s4 + 3][d]; hh.w = f2bf(f); ll.w = f2bf(f - bf2f(hh.w));
        const size_t vd = ((size_t)bh * 64 + d) * S_ + s0 + s4;
        *(ushort4*)(Vth + vd) = hh;
        *(ushort4*)(Vtl + vd) = ll;
    }
}

// ---------------------------------------------------------------------------
// Split-bf16 MFMA flash attention. Block = 256 thr = 4 waves; 128 q-rows
// per block (32 per wave, 2 m-frags); K-tile 64. All frag layouts identical
// to the validated GEMM. P converts C-layout -> A-layout via per-wave-
// private LDS (no barrier). 3-term split everywhere (err ~1e-5 rel).
// ---------------------------------------------------------------------------
__global__ __launch_bounds__(256) void attn_mfma_kernel(
    const float* __restrict__ Q,
    const unsigned short* __restrict__ Kh, const unsigned short* __restrict__ Kl,
    const unsigned short* __restrict__ Vth, const unsigned short* __restrict__ Vtl,
    float* __restrict__ O)
{
    __shared__ unsigned short Ksh[64 * 72], Ksl[64 * 72];   // [key][d]
    __shared__ unsigned short Vsh[64 * 72], Vsl[64 * 72];   // [d][key]
    __shared__ unsigned short Phs[4][32 * 72];              // per-wave [q][key]
    __shared__ unsigned short Pls[4][32 * 72];

    const int tid  = threadIdx.x;
    const int lane = tid & 63;
    const int w    = tid >> 6;
    const int l15  = lane & 15, g = lane >> 4;
    const int bh   = blockIdx.y;
    const int b    = bh >> 4, h = bh & 15;
    const int q0   = blockIdx.x * 128 + w * 32;
    const float scale = 0.125f;

    // Q fragments (scaled, split)
    bf16x8 qh[2][2], ql[2][2];
    #pragma unroll
    for (int mi = 0; mi < 2; ++mi)
        #pragma unroll
        for (int ks = 0; ks < 2; ++ks) {
            const float* qp = Q + ((size_t)(b * S_ + q0 + mi * 16 + l15)) * D_
                              + h * 64 + ks * 32 + g * 8;
            const float4 f0 = *(const float4*)qp;
            const float4 f1 = *(const float4*)(qp + 4);
            const float vs[8] = {f0.x * scale, f0.y * scale, f0.z * scale, f0.w * scale,
                                 f1.x * scale, f1.y * scale, f1.z * scale, f1.w * scale};
            #pragma unroll
            for (int j = 0; j < 8; ++j) {
                const unsigned short hv = f2bf(vs[j]);
                qh[mi][ks][j] = (short)hv;
                ql[mi][ks][j] = (short)f2bf(vs[j] - bf2f(hv));
            }
        }

    f32x4 o[2][4] = {};
    float mrun[2][4], lrun[2][4];
    #pragma unroll
    for (int mi = 0; mi < 2; ++mi)
        #pragma unroll
        for (int r = 0; r < 4; ++r) { mrun[mi][r] = -1e30f; lrun[mi][r] = 0.f; }

    const unsigned short* KhB = Kh  + (size_t)bh * S_ * 64;
    const unsigned short* KlB = Kl  + (size_t)bh * S_ * 64;
    const unsigned short* VhB = Vth + (size_t)bh * 64 * S_;
    const unsigned short* VlB = Vtl + (size_t)bh * 64 * S_;

    for (int kt = 0; kt < S_; kt += 64) {
        __syncthreads();
        #pragma unroll
        for (int u = 0; u < 2; ++u) {
            const int idx = tid + u * 256;      // 0..511
            const int rr  = idx >> 3;           // 0..63
            const int c8  = (idx & 7) * 8;      // 0..56
            *(uint4*)&Ksh[rr * 72 + c8] = *(const uint4*)(KhB + (size_t)(kt + rr) * 64 + c8);
            *(uint4*)&Ksl[rr * 72 + c8] = *(const uint4*)(KlB + (size_t)(kt + rr) * 64 + c8);
            *(uint4*)&Vsh[rr * 72 + c8] = *(const uint4*)(VhB + (size_t)rr * S_ + kt + c8);
            *(uint4*)&Vsl[rr * 72 + c8] = *(const uint4*)(VlB + (size_t)rr * S_ + kt + c8);
        }
        __syncthreads();

        // ---- scores S[32 q][64 key]
        f32x4 s[2][4] = {};
        #pragma unroll
        for (int ks = 0; ks < 2; ++ks)
            #pragma unroll
            for (int ni = 0; ni < 4; ++ni) {
                const bf16x8 khf = *(const bf16x8*)&Ksh[(ni * 16 + l15) * 72 + ks * 32 + g * 8];
                const bf16x8 klf = *(const bf16x8*)&Ksl[(ni * 16 + l15) * 72 + ks * 32 + g * 8];
                #pragma unroll
                for (int mi = 0; mi < 2; ++mi) {
                    s[mi][ni] = __builtin_amdgcn_mfma_f32_16x16x32_bf16(qh[mi][ks], khf, s[mi][ni], 0, 0, 0);
                    s[mi][ni] = __builtin_amdgcn_mfma_f32_16x16x32_bf16(qh[mi][ks], klf, s[mi][ni], 0, 0, 0);
                    s[mi][ni] = __builtin_amdgcn_mfma_f32_16x16x32_bf16(ql[mi][ks], khf, s[mi][ni], 0, 0, 0);
                }
            }

        // ---- online softmax (rows 4g+r per mi; 16-lane groups share a row)
        #pragma unroll
        for (int mi = 0; mi < 2; ++mi) {
            #pragma unroll
            for (int r = 0; r < 4; ++r) {
                float mx = fmaxf(fmaxf(s[mi][0][r], s[mi][1][r]),
                                 fmaxf(s[mi][2][r], s[mi][3][r]));
                mx = fmaxf(mx, __shfl_xor(mx, 1));
                mx = fmaxf(mx, __shfl_xor(mx, 2));
                mx = fmaxf(mx, __shfl_xor(mx, 4));
                mx = fmaxf(mx, __shfl_xor(mx, 8));
                const float mn = fmaxf(mrun[mi][r], mx);
                const float c  = __expf(mrun[mi][r] - mn);
                mrun[mi][r] = mn;
                float rs = 0.f;
                #pragma unroll
                for (int ni = 0; ni < 4; ++ni) {
                    const float p = __expf(s[mi][ni][r] - mn);
                    rs += p;
                    const unsigned short ph = f2bf(p);
                    const int off = (mi * 16 + 4 * g + r) * 72 + ni * 16 + l15;
                    Phs[w][off] = ph;
                    Pls[w][off] = f2bf(p - bf2f(ph));
                }
                rs += __shfl_xor(rs, 1);
                rs += __shfl_xor(rs, 2);
                rs += __shfl_xor(rs, 4);
                rs += __shfl_xor(rs, 8);
                lrun[mi][r] = lrun[mi][r] * c + rs;
                #pragma unroll
                for (int di = 0; di < 4; ++di) o[mi][di][r] *= c;
            }
        }

        // ---- PV (P from wave-private LDS; no barrier needed)
        #pragma unroll
        for (int ks = 0; ks < 2; ++ks) {
            bf16x8 pfh[2], pfl[2];
            #pragma unroll
            for (int mi = 0; mi < 2; ++mi) {
                pfh[mi] = *(const bf16x8*)&Phs[w][(mi * 16 + l15) * 72 + ks * 32 + g * 8];
                pfl[mi] = *(const bf16x8*)&Pls[w][(mi * 16 + l15) * 72 + ks * 32 + g * 8];
            }
            #pragma unroll
            for (int di = 0; di < 4; ++di) {
                const bf16x8 vhf = *(const bf16x8*)&Vsh[(di * 16 + l15) * 72 + ks * 32 + g * 8];
                const bf16x8 vlf = *(const bf16x8*)&Vsl[(di * 16 + l15) * 72 + ks * 32 + g * 8];
                #pragma unroll
                for (int mi = 0; mi < 2; ++mi) {
                    o[mi][di] = __builtin_amdgcn_mfma_f32_16x16x32_bf16(pfh[mi], vhf, o[mi][di], 0, 0, 0);
                    o[mi][di] = __builtin_amdgcn_mfma_f32_16x16x32_bf16(pfh[mi], vlf, o[mi][di], 0, 0, 0);
                    o[mi][di] = __builtin_amdgcn_mfma_f32_16x16x32_bf16(pfl[mi], vhf, o[mi][di], 0, 0, 0);
                }
            }
        }
    }

    // ---- epilogue
    #pragma unroll
    for (int mi = 0; mi < 2; ++mi)
        #pragma unroll
        for (int r = 0; r < 4; ++r) {
            const float inv = 1.f / lrun[mi][r];
            float* op = O + ((size_t)(b * S_ + q0 + mi * 16 + 4 * g + r)) * D_
                        + h * 64 + l15;
            #pragma unroll
            for (int di = 0; di < 4; ++di) op[di * 16] = o[mi][di][r] * inv;
        }
}

// ---------------------------------------------------------------------------
// out[row,:] = R[row,:] + LN(Y[row,:]) * g + beta
// ---------------------------------------------------------------------------
__global__ __launch_bounds__(256) void add_ln_kernel(
    const float* __restrict__ Y, const float* __restrict__ R,
    const float* __restrict__ g, const float* __restrict__ beta,
    float* __restrict__ out)
{
    const int row = blockIdx.x;
    const int tid = threadIdx.x;
    __shared__ float r1[4], r2[4];

    const float4 v = *(const float4*)(Y + (size_t)row * D_ + tid * 4);
    float s1 = v.x + v.y + v.z + v.w;
    float s2 = v.x * v.x + v.y * v.y + v.z * v.z + v.w * v.w;
    #pragma unroll
    for (int off = 32; off >= 1; off >>= 1) {
        s1 += __shfl_xor(s1, off);
        s2 += __shfl_xor(s2, off);
    }
    if ((tid & 63) == 0) { r1[tid >> 6] = s1; r2[tid >> 6] = s2; }
    __syncthreads();
    s1 = r1[0] + r1[1] + r1[2] + r1[3];
    s2 = r2[0] + r2[1] + r2[2] + r2[3];
    const float mu  = s1 * (1.f / D_);
    const float var = s2 * (1.f / D_) - mu * mu;
    const float rs  = rsqrtf(var + EPS_);

    const float4 rr = *(const float4*)(R + (size_t)row * D_ + tid * 4);
    const float4 gg = *(const float4*)(g + tid * 4);
    const float4 bb = *(const float4*)(beta + tid * 4);
    float4 o;
    o.x = rr.x + (v.x - mu) * rs * gg.x + bb.x;
    o.y = rr.y + (v.y - mu) * rs * gg.y + bb.y;
    o.z = rr.z + (v.z - mu) * rs * gg.z + bb.z;
    o.w = rr.w + (v.w - mu) * rs * gg.w + bb.w;
    *(float4*)(out + (size_t)row * D_ + tid * 4) = o;
}

// ---------------------------------------------------------------------------
extern "C" void kernel_launch(void* const* d_in, const int* in_sizes, int n_in,
                              void* d_out, int out_size, void* d_ws, size_t ws_size,
                              hipStream_t stream)
{
    const float* x  = (const float*)d_in[0];
    const float* LO = (const float*)d_in[1];
    const float* Wq  = (const float*)d_in[2];
    const float* bq_ = (const float*)d_in[3];
    const float* gq  = (const float*)d_in[4];
    const float* beq = (const float*)d_in[5];
    const float* Wk  = (const float*)d_in[6];
    const float* bk_ = (const float*)d_in[7];
    const float* gk  = (const float*)d_in[8];
    const float* bek = (const float*)d_in[9];
    const float* Wv  = (const float*)d_in[10];
    const float* bv_ = (const float*)d_in[11];
    const float* gv  = (const float*)d_in[12];
    const float* bev = (const float*)d_in[13];
    const float* Wo  = (const float*)d_in[14];
    const float* bo  = (const float*)d_in[15];
    const float* ang = (const float*)d_in[16];
    const float* anb = (const float*)d_in[17];
    const float* W1  = (const float*)d_in[18];
    const float* b1  = (const float*)d_in[19];
    const float* W2  = (const float*)d_in[20];
    const float* b2  = (const float*)d_in[21];
    const float* fng = (const float*)d_in[22];
    const float* fnb = (const float*)d_in[23];

    const size_t BS  = (size_t)B_ * S_;          // 4096 rows
    const size_t SEG = BS * D_;                  // 4M floats
    float* ws  = (float*)d_ws;
    float* ns   = ws;                            // 4M  (later: attn out)
    float* bufq = ws + SEG;                      // 4M  (later: attn proj out)
    float* bufk = ws + 2 * SEG;                  // 4M  (later: resid1)
    float* bufv = ws + 3 * SEG;                  // 4M  (later: ffn2 out)
    float* big  = ws + 4 * SEG;                  // 16M (GRN staging / KV splits / FFN hidden)

    // Pre-split transposed weights (bf16 bits), after the fp32 region
    unsigned short* wt = (unsigned short*)(ws + 8 * SEG);
    const size_t MM = 1048576;
    unsigned short* wtq_h = wt;            unsigned short* wtq_l = wt + MM;
    unsigned short* wtk_h = wt + 2 * MM;   unsigned short* wtk_l = wt + 3 * MM;
    unsigned short* wtv_h = wt + 4 * MM;   unsigned short* wtv_l = wt + 5 * MM;
    unsigned short* wto_h = wt + 6 * MM;   unsigned short* wto_l = wt + 7 * MM;
    unsigned short* w1_h  = wt + 8 * MM;   unsigned short* w1_l  = wt + 12 * MM;
    unsigned short* w2_h  = wt + 16 * MM;  unsigned short* w2_l  = wt + 20 * MM;

    // K/V hi/lo splits live in `big` (free between GRN staging and FFN1)
    const size_t KVSEG = (size_t)B_ * H_ * S_ * HD_;   // 4M elements
    unsigned short* kv  = (unsigned short*)big;
    unsigned short* kh_ = kv;
    unsigned short* kl_ = kv + KVSEG;
    unsigned short* vth = kv + 2 * KVSEG;
    unsigned short* vtl = kv + 3 * KVSEG;

    const dim3 blk(256);

    // 0. weight transpose + hi/lo split
    wconv_kernel<<<dim3(32, 32),  blk, 0, stream>>>(Wq, wtq_h, wtq_l, D_, D_);
    wconv_kernel<<<dim3(32, 32),  blk, 0, stream>>>(Wk, wtk_h, wtk_l, D_, D_);
    wconv_kernel<<<dim3(32, 32),  blk, 0, stream>>>(Wv, wtv_h, wtv_l, D_, D_);
    wconv_kernel<<<dim3(32, 32),  blk, 0, stream>>>(Wo, wto_h, wto_l, D_, D_);
    wconv_kernel<<<dim3(128, 32), blk, 0, stream>>>(W1, w1_h,  w1_l,  D_, MLP_);
    wconv_kernel<<<dim3(32, 128), blk, 0, stream>>>(W2, w2_h,  w2_l,  MLP_, D_);

    // 1. shared normalized sum
    grn_ns_kernel<<<dim3(BS), blk, 0, stream>>>(LO, ns);

    // 2. GRN q/k/v
    const unsigned short* Wh[3] = {wtq_h, wtk_h, wtv_h};
    const unsigned short* Wl[3] = {wtq_l, wtk_l, wtv_l};
    const float* bp[3]  = {bq_, bk_, bv_};
    const float* gp[3]  = {gq, gk, gv};
    const float* bep[3] = {beq, bek, bev};
    float* outp[3] = {bufq, bufk, bufv};
    for (int p = 0; p < 3; ++p) {
        gemm_bf16s_kernel<1><<<dim3(D_ / 128, (B_ * L_ * S_) / 128), blk, 0, stream>>>(
            LO, Wh[p], Wl[p], bp[p], big, B_ * L_ * S_, D_, D_);
        grn_reduce_kernel<<<dim3(BS), blk, 0, stream>>>(big, ns, gp[p], bep[p], outp[p]);
    }

    // 3. K/V split + transpose, then MFMA flash attention -> ns (reused)
    kvconv_kernel<<<dim3(S_ / 64, B_ * H_), blk, 0, stream>>>(bufk, bufv, kh_, kl_, vth, vtl);
    attn_mfma_kernel<<<dim3(S_ / 128, B_ * H_), blk, 0, stream>>>(bufq, kh_, kl_, vth, vtl, ns);

    // 4. attn out projection -> bufq (reused)
    gemm_bf16s_kernel<0><<<dim3(D_ / 128, BS / 128), blk, 0, stream>>>(
        ns, wto_h, wto_l, bo, bufq, (int)BS, D_, D_);

    // 5. resid1 = x + LN(attn_proj) -> bufk (reused)
    add_ln_kernel<<<dim3(BS), blk, 0, stream>>>(bufq, x, ang, anb, bufk);

    // 6. FFN1: gelu(resid1 @ W1 + b1) -> big
    gemm_bf16s_kernel<2><<<dim3(MLP_ / 128, BS / 128), blk, 0, stream>>>(
        bufk, w1_h, w1_l, b1, big, (int)BS, MLP_, D_);

    // 7. FFN2: big @ W2 + b2 -> bufv (reused)
    gemm_bf16s_kernel<0><<<dim3(D_ / 128, BS / 128), blk, 0, stream>>>(
        big, w2_h, w2_l, b2, bufv, (int)BS, D_, MLP_);

    // 8. out = resid1 + LN(ffn2)
    add_ln_kernel<<<dim3(BS), blk, 0, stream>>>(bufv, bufk, fng, fnb, (float*)d_out);
}